// Round 1
// baseline (714.339 us; speedup 1.0000x reference)
//
#include <hip/hip_runtime.h>

typedef unsigned short u16;
typedef __attribute__((ext_vector_type(8))) short short8;
typedef __attribute__((ext_vector_type(4))) float f32x4;

#define NAG 15
#define NB 32768
#define NEG_BIG -1e30f

__device__ __forceinline__ u16 f2bf(float x){
  unsigned int u = __float_as_uint(x);
  u += 0x7fffu + ((u >> 16) & 1u);
  return (u16)(u >> 16);
}
__device__ __forceinline__ float bf2f(short h){
  return __uint_as_float(((unsigned int)(u16)h) << 16);
}

// ---------------- K0: weight convert/transpose to bf16 [N][K] ----------------
__global__ __launch_bounds__(256) void k0_conv(
    const float* __restrict__ Wenc, const float* __restrict__ Wsenc,
    const float* __restrict__ Wk, const float* __restrict__ Wsel, const float* __restrict__ Wv,
    const float* __restrict__ Wc1, const float* __restrict__ Wc2,
    u16* __restrict__ WencB, u16* __restrict__ WsencB,
    u16* __restrict__ WkB, u16* __restrict__ WvB, u16* __restrict__ WselB,
    u16* __restrict__ Wc1B, u16* __restrict__ Wc2B)
{
  int idx = blockIdx.x * 256 + threadIdx.x;
  if (idx < 307200){                       // WencB[a][n<128][k<160] = Wenc[a][k][n]
    int a = idx / 20480, r = idx % 20480, n = r / 160, k = r % 160;
    WencB[idx] = f2bf(Wenc[a*20480 + k*128 + n]);
  } else if (idx < 552960){                // WsencB[a][n][k] 128x128
    int i = idx - 307200; int a = i / 16384, r = i % 16384, n = r / 128, k = r % 128;
    WsencB[i] = f2bf(Wsenc[a*16384 + k*128 + n]);
  } else if (idx < 569344){                // WkB[c=nh*32+d][k<128] = Wk[nh][k][d]
    int i = idx - 552960; int c = i / 128, k = i % 128;
    WkB[i] = f2bf(Wk[(c>>5)*4096 + k*32 + (c&31)]);
  } else if (idx < 585728){
    int i = idx - 569344; int c = i / 128, k = i % 128;
    WvB[i] = f2bf(Wv[(c>>5)*4096 + k*32 + (c&31)]);
  } else if (idx < 602112){
    int i = idx - 585728; int c = i / 128, k = i % 128;
    WselB[i] = f2bf(Wsel[(c>>5)*4096 + k*32 + (c&31)]);
  } else if (idx < 1093632){               // Wc1B[a][n<128][k<256] = Wc1[a][k][n]
    int i = idx - 602112; int a = i / 32768, r = i % 32768, n = r / 256, k = r % 256;
    Wc1B[i] = f2bf(Wc1[a*32768 + k*128 + n]);
  } else if (idx < 1155072){               // Wc2B[a][n<32][k<128] = Wc2[a][k][n]
    int i = idx - 1093632; int a = i / 4096, r = i % 4096, n = r / 128, k = r % 128;
    Wc2B[i] = f2bf(Wc2[a*4096 + k*32 + n]);
  }
}

// ---------------- shared GEMM helpers ----------------
// A in LDS: row-major bf16, 16B slots XOR-swizzled: slot' = slot ^ (row & mask)
// B in global: bf16 [N][K], lane reads 8 contiguous k.
__device__ __forceinline__ void mfma_block(const char* lds, int aOff, int aStride, int aMask,
    const u16* __restrict__ B, int bld, int ksteps,
    int m0, int c0, int l15, int l4, f32x4 acc[4][2])
{
  for (int ks = 0; ks < ksteps; ++ks){
    short8 af[4];
    #pragma unroll
    for (int fm = 0; fm < 4; ++fm){
      int row = m0 + fm*16 + l15;
      int slot = ks*4 + l4;
      af[fm] = *(const short8*)(lds + aOff + row*aStride + ((slot ^ (row & aMask)) << 4));
    }
    short8 bf[2];
    #pragma unroll
    for (int fn = 0; fn < 2; ++fn){
      int n = c0 + fn*16 + l15;
      bf[fn] = *(const short8*)(B + (size_t)n*bld + ks*32 + l4*8);
    }
    #pragma unroll
    for (int fm = 0; fm < 4; ++fm)
      #pragma unroll
      for (int fn = 0; fn < 2; ++fn)
        acc[fm][fn] = __builtin_amdgcn_mfma_f32_16x16x32_bf16(af[fm], bf[fn], acc[fm][fn], 0, 0, 0);
  }
}

// epilogue: bias + optional lrelu, store bf16 to swizzled LDS tile (stride 256B) and/or linear LDS tile
__device__ __forceinline__ void epi_store(char* lds, f32x4 acc[4][2], const float* __restrict__ bias,
    bool act, int m0, int c0, int l15, int l4, int swzOff, int linOff)
{
  #pragma unroll
  for (int fm = 0; fm < 4; ++fm)
  #pragma unroll
  for (int fn = 0; fn < 2; ++fn){
    int col = c0 + fn*16 + l15;
    float bb = bias ? bias[col] : 0.0f;
    #pragma unroll
    for (int q = 0; q < 4; ++q){
      int row = m0 + fm*16 + l4*4 + q;
      float v = acc[fm][fn][q] + bb;
      if (act) v = v > 0.0f ? v : 0.01f * v;
      u16 h = f2bf(v);
      if (swzOff >= 0) *(u16*)(lds + swzOff + row*256 + (((col>>3) ^ (row&7))<<4) + ((col&7)<<1)) = h;
      if (linOff >= 0) *(u16*)(lds + linOff + row*256 + col*2) = h;
    }
  }
}

__device__ __forceinline__ void copy_out_bf16(const char* lds, int off, u16* __restrict__ dst,
                                              int a, int b0, int t)
{
  #pragma unroll
  for (int it = 0; it < 4; ++it){
    int e = t + it*512;
    int row = e >> 4, cb = e & 15;
    *(short8*)(dst + ((size_t)a*NB + b0 + row)*128 + cb*8) =
        *(const short8*)(lds + off + row*256 + cb*16);
  }
}

// ---------------- K1: encoders + k/v/sel projections ----------------
#define S_OFF 0
#define AC_OFF 32768
#define SA_OFF 40960
#define SE_OFF 73728
#define K1_LDS 106496

__global__ __launch_bounds__(512) void k1_enc(
    const float* __restrict__ states, const float* __restrict__ actions,
    const float* __restrict__ benc, const float* __restrict__ bsenc, const float* __restrict__ bvp,
    const u16* __restrict__ WencB, const u16* __restrict__ WsencB,
    const u16* __restrict__ WkB, const u16* __restrict__ WvB, const u16* __restrict__ WselB,
    u16* __restrict__ senc_g, u16* __restrict__ keys_g, u16* __restrict__ vals_g, u16* __restrict__ sel_g)
{
  extern __shared__ __align__(16) char lds[];
  const int a = blockIdx.y;
  const int b0 = blockIdx.x * 128;
  const int t = threadIdx.x;
  const int lane = t & 63, w = t >> 6;
  const int m0 = (w >> 2) * 64, c0 = (w & 3) * 32;
  const int l15 = lane & 15, l4 = lane >> 4;

  // stage states -> S swizzled bf16 [128][128]
  #pragma unroll
  for (int it = 0; it < 4; ++it){
    int e = t + it*512, row = e >> 4, cb = e & 15;
    const float* sp = states + ((size_t)a*NB + b0 + row)*128 + cb*8;
    float4 v0 = *(const float4*)sp, v1 = *(const float4*)(sp + 4);
    short8 p;
    p[0]=(short)f2bf(v0.x); p[1]=(short)f2bf(v0.y); p[2]=(short)f2bf(v0.z); p[3]=(short)f2bf(v0.w);
    p[4]=(short)f2bf(v1.x); p[5]=(short)f2bf(v1.y); p[6]=(short)f2bf(v1.z); p[7]=(short)f2bf(v1.w);
    *(short8*)(lds + S_OFF + row*256 + ((cb ^ (row&7))<<4)) = p;
  }
  { // actions -> AC swizzled bf16 [128][32]
    int row = t >> 2, cb = t & 3;
    const float* ap = actions + ((size_t)a*NB + b0 + row)*32 + cb*8;
    float4 v0 = *(const float4*)ap, v1 = *(const float4*)(ap + 4);
    short8 p;
    p[0]=(short)f2bf(v0.x); p[1]=(short)f2bf(v0.y); p[2]=(short)f2bf(v0.z); p[3]=(short)f2bf(v0.w);
    p[4]=(short)f2bf(v1.x); p[5]=(short)f2bf(v1.y); p[6]=(short)f2bf(v1.z); p[7]=(short)f2bf(v1.w);
    *(short8*)(lds + AC_OFF + row*64 + ((cb ^ (row&3))<<4)) = p;
  }
  __syncthreads();

  f32x4 acc[4][2];

  // GEMM1: sa_enc = lrelu([S|Ac] @ Wenc + benc), K = 160
  #pragma unroll
  for (int fm = 0; fm < 4; ++fm){ acc[fm][0] = (f32x4)0.0f; acc[fm][1] = (f32x4)0.0f; }
  mfma_block(lds, S_OFF, 256, 7, WencB + (size_t)a*20480, 160, 4, m0, c0, l15, l4, acc);
  { // ks = 4: k = 128..159 from actions tile
    short8 af[4];
    #pragma unroll
    for (int fm = 0; fm < 4; ++fm){
      int row = m0 + fm*16 + l15;
      af[fm] = *(const short8*)(lds + AC_OFF + row*64 + ((l4 ^ (row&3))<<4));
    }
    short8 bf[2];
    #pragma unroll
    for (int fn = 0; fn < 2; ++fn){
      int n = c0 + fn*16 + l15;
      bf[fn] = *(const short8*)(WencB + (size_t)a*20480 + (size_t)n*160 + 128 + l4*8);
    }
    #pragma unroll
    for (int fm = 0; fm < 4; ++fm)
      #pragma unroll
      for (int fn = 0; fn < 2; ++fn)
        acc[fm][fn] = __builtin_amdgcn_mfma_f32_16x16x32_bf16(af[fm], bf[fn], acc[fm][fn], 0, 0, 0);
  }
  epi_store(lds, acc, benc + a*128, true, m0, c0, l15, l4, SA_OFF, -1);
  __syncthreads();

  // GEMM2: s_enc = lrelu(S @ Wsenc + bsenc)
  #pragma unroll
  for (int fm = 0; fm < 4; ++fm){ acc[fm][0] = (f32x4)0.0f; acc[fm][1] = (f32x4)0.0f; }
  mfma_block(lds, S_OFF, 256, 7, WsencB + (size_t)a*16384, 128, 4, m0, c0, l15, l4, acc);
  __syncthreads();  // S fully consumed; OUT (offset 0) aliases S
  epi_store(lds, acc, bsenc + a*128, true, m0, c0, l15, l4, SE_OFF, 0);
  __syncthreads();
  copy_out_bf16(lds, 0, senc_g, a, b0, t);
  __syncthreads();

  // GEMM3: keys = sa_enc @ Wk
  #pragma unroll
  for (int fm = 0; fm < 4; ++fm){ acc[fm][0] = (f32x4)0.0f; acc[fm][1] = (f32x4)0.0f; }
  mfma_block(lds, SA_OFF, 256, 7, WkB, 128, 4, m0, c0, l15, l4, acc);
  epi_store(lds, acc, (const float*)nullptr, false, m0, c0, l15, l4, -1, 0);
  __syncthreads();
  copy_out_bf16(lds, 0, keys_g, a, b0, t);
  __syncthreads();

  // GEMM4: vals = lrelu(sa_enc @ Wv + bv)
  #pragma unroll
  for (int fm = 0; fm < 4; ++fm){ acc[fm][0] = (f32x4)0.0f; acc[fm][1] = (f32x4)0.0f; }
  mfma_block(lds, SA_OFF, 256, 7, WvB, 128, 4, m0, c0, l15, l4, acc);
  epi_store(lds, acc, bvp, true, m0, c0, l15, l4, -1, 0);
  __syncthreads();
  copy_out_bf16(lds, 0, vals_g, a, b0, t);
  __syncthreads();

  // GEMM5: sel = s_enc @ Wsel
  #pragma unroll
  for (int fm = 0; fm < 4; ++fm){ acc[fm][0] = (f32x4)0.0f; acc[fm][1] = (f32x4)0.0f; }
  mfma_block(lds, SE_OFF, 256, 7, WselB, 128, 4, m0, c0, l15, l4, acc);
  epi_store(lds, acc, (const float*)nullptr, false, m0, c0, l15, l4, -1, 0);
  __syncthreads();
  copy_out_bf16(lds, 0, sel_g, a, b0, t);
}

// ---------------- K2a: exclude-self attention over agents ----------------
#define K2A_LDS 130560

__global__ __launch_bounds__(512) void k2a_attn(
    const u16* __restrict__ keys_g, const u16* __restrict__ vals_g,
    const u16* __restrict__ sel_g, u16* __restrict__ attn_g)
{
  extern __shared__ __align__(16) char lds[];
  const int b0 = blockIdx.x * 16;
  const int t = threadIdx.x;
  // stage keys+vals tiles: [15][16][128] bf16, padded row 136 elems (272B)
  for (int it = 0; it < 8; ++it){
    int e = t + it*512;
    if (e < 3840){
      int j = e >> 8, r = (e >> 4) & 15, c = e & 15;
      size_t src = ((size_t)j*NB + b0 + r)*128 + c*8;
      int dst = (j*16 + r)*272 + c*16;
      *(short8*)(lds + dst) = *(const short8*)(keys_g + src);
      *(short8*)(lds + 65280 + dst) = *(const short8*)(vals_g + src);
    }
  }
  __syncthreads();
  for (int e = t; e < 960; e += 512){
    int b = e & 15, n = (e >> 4) & 3, i = e >> 6;
    size_t base = ((size_t)i*NB + b0 + b)*128 + n*32;
    float sf[32];
    #pragma unroll
    for (int c4 = 0; c4 < 4; ++c4){
      short8 s8 = *(const short8*)(sel_g + base + c4*8);
      #pragma unroll
      for (int x = 0; x < 8; ++x) sf[c4*8+x] = bf2f(s8[x]);
    }
    float lg[15]; float mx = NEG_BIG;
    #pragma unroll
    for (int j = 0; j < 15; ++j){
      if (j == i){ lg[j] = NEG_BIG; continue; }
      int kb = (j*16 + b)*272 + n*64;
      float d = 0.f;
      #pragma unroll
      for (int c4 = 0; c4 < 4; ++c4){
        short8 k8 = *(const short8*)(lds + kb + c4*16);
        #pragma unroll
        for (int x = 0; x < 8; ++x) d += bf2f(k8[x]) * sf[c4*8+x];
      }
      d *= 0.17677669529663687f;   // 1/sqrt(32)
      lg[j] = d; mx = fmaxf(mx, d);
    }
    float sum = 0.f;
    #pragma unroll
    for (int j = 0; j < 15; ++j){
      float p = (j == i) ? 0.f : __expf(lg[j] - mx);
      lg[j] = p; sum += p;
    }
    float inv = 1.0f / sum;
    float oacc[32];
    #pragma unroll
    for (int x = 0; x < 32; ++x) oacc[x] = 0.f;
    #pragma unroll
    for (int j = 0; j < 15; ++j){
      if (j == i) continue;
      float p = lg[j];
      int vb = 65280 + (j*16 + b)*272 + n*64;
      #pragma unroll
      for (int c4 = 0; c4 < 4; ++c4){
        short8 v8 = *(const short8*)(lds + vb + c4*16);
        #pragma unroll
        for (int x = 0; x < 8; ++x) oacc[c4*8+x] += p * bf2f(v8[x]);
      }
    }
    #pragma unroll
    for (int c4 = 0; c4 < 4; ++c4){
      short8 o;
      #pragma unroll
      for (int x = 0; x < 8; ++x) o[x] = (short)f2bf(oacc[c4*8+x] * inv);
      *(short8*)(attn_g + base + c4*8) = o;   // attn aliases keys: same tile, keys already staged
    }
  }
}

// ---------------- K2b: critic head ----------------
#define AIN_OFF 0
#define HL_OFF 65536
#define O2_OFF 98304
#define K2B_LDS 114688

__global__ __launch_bounds__(512) void k2b_critic(
    const u16* __restrict__ senc_g, const u16* __restrict__ attn_g,
    const u16* __restrict__ Wc1B, const u16* __restrict__ Wc2B,
    const float* __restrict__ bc1, const float* __restrict__ bc2,
    float* __restrict__ outp)
{
  extern __shared__ __align__(16) char lds[];
  const int a = blockIdx.y, b0 = blockIdx.x * 128, t = threadIdx.x;
  const int lane = t & 63, w = t >> 6;
  const int m0 = (w >> 2)*64, c0 = (w & 3)*32;
  const int l15 = lane & 15, l4 = lane >> 4;

  // stage [s_enc | attn] -> Ain swizzled bf16 [128][256] (stride 512B, 32 slots)
  #pragma unroll
  for (int it = 0; it < 4; ++it){
    int e = t + it*512, row = e >> 4, cb = e & 15;
    size_t src = ((size_t)a*NB + b0 + row)*128 + cb*8;
    short8 v = *(const short8*)(senc_g + src);
    *(short8*)(lds + AIN_OFF + row*512 + ((cb ^ (row&7))<<4)) = v;
    short8 v2 = *(const short8*)(attn_g + src);
    *(short8*)(lds + AIN_OFF + row*512 + (((16 + cb) ^ (row&7))<<4)) = v2;
  }
  __syncthreads();

  f32x4 acc[4][2];
  #pragma unroll
  for (int fm = 0; fm < 4; ++fm){ acc[fm][0] = (f32x4)0.0f; acc[fm][1] = (f32x4)0.0f; }
  mfma_block(lds, AIN_OFF, 512, 7, Wc1B + (size_t)a*32768, 256, 8, m0, c0, l15, l4, acc);
  epi_store(lds, acc, bc1 + a*128, true, m0, c0, l15, l4, HL_OFF, -1);
  __syncthreads();

  // GEMM-q: out[128,32] = h @ Wc2 + bc2 ; waves: rows (w>>1)*32, cols (w&1)*16
  const int r0 = (w >> 1)*32, cq = (w & 1)*16;
  f32x4 aq[2]; aq[0] = (f32x4)0.0f; aq[1] = (f32x4)0.0f;
  for (int ks = 0; ks < 4; ++ks){
    short8 af[2];
    #pragma unroll
    for (int fm = 0; fm < 2; ++fm){
      int row = r0 + fm*16 + l15, slot = ks*4 + l4;
      af[fm] = *(const short8*)(lds + HL_OFF + row*256 + ((slot ^ (row&7))<<4));
    }
    int n = cq + l15;
    short8 bq = *(const short8*)(Wc2B + (size_t)a*4096 + (size_t)n*128 + ks*32 + l4*8);
    aq[0] = __builtin_amdgcn_mfma_f32_16x16x32_bf16(af[0], bq, aq[0], 0, 0, 0);
    aq[1] = __builtin_amdgcn_mfma_f32_16x16x32_bf16(af[1], bq, aq[1], 0, 0, 0);
  }
  {
    int col = cq + l15; float bb = bc2[a*32 + col];
    #pragma unroll
    for (int fm = 0; fm < 2; ++fm)
      #pragma unroll
      for (int q = 0; q < 4; ++q){
        int row = r0 + fm*16 + l4*4 + q;
        *(float*)(lds + O2_OFF + (row*32 + col)*4) = aq[fm][q] + bb;
      }
  }
  __syncthreads();
  #pragma unroll
  for (int it = 0; it < 2; ++it){
    int e = t + it*512;
    float4 v = *(const float4*)(lds + O2_OFF + e*16);
    *(float4*)(outp + ((size_t)a*NB + b0 + (e>>3))*32 + (e&7)*4) = v;
  }
}

// ---------------- launch ----------------
extern "C" void kernel_launch(void* const* d_in, const int* in_sizes, int n_in,
                              void* d_out, int out_size, void* d_ws, size_t ws_size,
                              hipStream_t stream)
{
  const float* states  = (const float*)d_in[0];
  const float* actions = (const float*)d_in[1];
  const float* Wenc    = (const float*)d_in[2];
  const float* benc    = (const float*)d_in[3];
  const float* Wsenc   = (const float*)d_in[4];
  const float* bsenc   = (const float*)d_in[5];
  const float* Wk      = (const float*)d_in[6];
  const float* Wsel    = (const float*)d_in[7];
  const float* Wv      = (const float*)d_in[8];
  const float* bv      = (const float*)d_in[9];
  const float* Wc1     = (const float*)d_in[10];
  const float* bc1     = (const float*)d_in[11];
  const float* Wc2     = (const float*)d_in[12];
  const float* bc2     = (const float*)d_in[13];

  char* ws = (char*)d_ws;
  u16* WencB  = (u16*)(ws + 0);
  u16* WsencB = (u16*)(ws + 614400);
  u16* WkB    = (u16*)(ws + 1105920);
  u16* WvB    = (u16*)(ws + 1138688);
  u16* WselB  = (u16*)(ws + 1171456);
  u16* Wc1B   = (u16*)(ws + 1204224);
  u16* Wc2B   = (u16*)(ws + 2187264);
  u16* senc_g = (u16*)(ws + 2310144);
  u16* keys_g = (u16*)(ws + 128139264);   // attn output aliases this
  u16* vals_g = (u16*)(ws + 253968384);
  u16* sel_g  = (u16*)(ws + 379797504);
  if (ws_size < 505626624ULL) return;     // need ~482 MB of scratch

  hipFuncSetAttribute((const void*)k1_enc,     hipFuncAttributeMaxDynamicSharedMemorySize, K1_LDS);
  hipFuncSetAttribute((const void*)k2a_attn,   hipFuncAttributeMaxDynamicSharedMemorySize, K2A_LDS);
  hipFuncSetAttribute((const void*)k2b_critic, hipFuncAttributeMaxDynamicSharedMemorySize, K2B_LDS);

  k0_conv<<<4512, 256, 0, stream>>>(Wenc, Wsenc, Wk, Wsel, Wv, Wc1, Wc2,
                                    WencB, WsencB, WkB, WvB, WselB, Wc1B, Wc2B);
  k1_enc<<<dim3(256, 15), 512, K1_LDS, stream>>>(states, actions, benc, bsenc, bv,
                                                 WencB, WsencB, WkB, WvB, WselB,
                                                 senc_g, keys_g, vals_g, sel_g);
  k2a_attn<<<2048, 512, K2A_LDS, stream>>>(keys_g, vals_g, sel_g, keys_g);
  k2b_critic<<<dim3(256, 15), 512, K2B_LDS, stream>>>(senc_g, keys_g, Wc1B, Wc2B,
                                                      bc1, bc2, (float*)d_out);
}